// Round 8
// baseline (97.308 us; speedup 1.0000x reference)
//
#include <hip/hip_runtime.h>
#include <hip/hip_fp16.h>

// QuantLinear: out[16][11008] = x[16][4096] . dequant(weight_q[11008][4096])^T + bias
// Harness promotes fp16 tensors to fp32 -> x/scale/zero/bias are float*.
// DIAGNOSTIC ROUND: the weight stream is pinned at ~3.5 TB/s across every
// structural variant (occupancy x4, atomics, LDS-coalesced staging). Two
// remaining hypotheses: (H5) fixed graph/launch overhead F inflates dur_us and
// the kernel is already near the ~29us floor; (H1) ~3.5 TB/s is the true
// read-path ceiling. Experiment: dispatch the IDENTICAL kernel twice
// (deterministic: writes the same values twice). dur ~= F + T_hbm + T_L3warm.
//   ~95-102us -> F~0, L3 reads no faster -> read wall is real.
//   ~69-85us  -> large F and/or fast L3 -> true T ~31-38us, near floor.
// Kernel body = round-5 single-kernel version (best so far, 51.2us).

typedef _Float16 v8hf __attribute__((ext_vector_type(8)));
typedef float v4f __attribute__((ext_vector_type(4)));

#define O_DIM 11008
#define I_DIM 4096
#define NGROUP 32   // I_DIM / 128

__global__ __launch_bounds__(256) void qgemm(const float* __restrict__ x,
                                             const int* __restrict__ wq,
                                             const float* __restrict__ scale,
                                             const float* __restrict__ zero,
                                             const float* __restrict__ bias,
                                             float* __restrict__ out) {
    __shared__ float red[4][256];

    const int ot  = blockIdx.x;    // o-tile 0..687
    const int tid = threadIdx.x;
    const int w   = tid >> 6;      // wave 0..3 -> K-quarter
    const int l   = tid & 63;
    const int col = l & 15;        // A-row = x-row / B-col = o (within tile)
    const int kb  = l >> 4;        // k sub-block 0..3
    const int o   = ot * 16 + col;

    const int*   __restrict__ wrow = wq + (size_t)o * I_DIM;
    const float* __restrict__ xrow = x  + (size_t)col * I_DIM;

    v4f acc = {0.f, 0.f, 0.f, 0.f};

    // Wave w handles scale-groups [w*8, w*8+8) = K range [w*1024, (w+1)*1024).
#pragma unroll 2
    for (int gi = 0; gi < 8; ++gi) {
        const int g = w * 8 + gi;
        const float s   = scale[o * NGROUP + g];
        const float z   = zero [o * NGROUP + g];
        const float nzs = -z * s;
#pragma unroll
        for (int ks = 0; ks < 4; ++ks) {
            const int i0 = g * 128 + ks * 32 + kb * 8;   // this lane's 8 k's
            const int4   q0 = *(const int4*)  (wrow + i0);
            const int4   q1 = *(const int4*)  (wrow + i0 + 4);
            const float4 x0 = *(const float4*)(xrow + i0);
            const float4 x1 = *(const float4*)(xrow + i0 + 4);
            v8hf a;
            a[0] = (_Float16)x0.x; a[1] = (_Float16)x0.y;
            a[2] = (_Float16)x0.z; a[3] = (_Float16)x0.w;
            a[4] = (_Float16)x1.x; a[5] = (_Float16)x1.y;
            a[6] = (_Float16)x1.z; a[7] = (_Float16)x1.w;
            // B-frag: same (lane,j)->k mapping as A => internal permutation cancels.
            v8hf bf;
            bf[0] = (_Float16)((float)(q0.x & 255) * s + nzs);
            bf[1] = (_Float16)((float)(q0.y & 255) * s + nzs);
            bf[2] = (_Float16)((float)(q0.z & 255) * s + nzs);
            bf[3] = (_Float16)((float)(q0.w & 255) * s + nzs);
            bf[4] = (_Float16)((float)(q1.x & 255) * s + nzs);
            bf[5] = (_Float16)((float)(q1.y & 255) * s + nzs);
            bf[6] = (_Float16)((float)(q1.z & 255) * s + nzs);
            bf[7] = (_Float16)((float)(q1.w & 255) * s + nzs);
            acc = __builtin_amdgcn_mfma_f32_16x16x32_f16(a, bf, acc, 0, 0, 0);
        }
    }

    // Cross-wave K-reduction. acc[r] = tile element (row=(l>>4)*4+r, col=l&15).
    *(v4f*)&red[w][l * 4] = acc;   // lane-contiguous 16B stores, conflict-free
    __syncthreads();

    // 256 threads: sum 4 waves' partials, add bias, store (each element once).
    const int t   = tid;
    const float sum = red[0][t] + red[1][t] + red[2][t] + red[3][t];
    const int l2  = t >> 2;                 // original lane
    const int r   = t & 3;                  // acc register index
    const int row = (l2 >> 4) * 4 + r;      // x-row 0..15
    const int oc  = ot * 16 + (l2 & 15);    // output column
    out[(size_t)row * O_DIM + oc] = sum + bias[oc];
}

extern "C" void kernel_launch(void* const* d_in, const int* in_sizes, int n_in,
                              void* d_out, int out_size, void* d_ws, size_t ws_size,
                              hipStream_t stream) {
    const float* x   = (const float*)d_in[0];
    const int*   wqp = (const int*)  d_in[1];
    const float* sc  = (const float*)d_in[2];
    const float* zp  = (const float*)d_in[3];
    const float* bp  = (const float*)d_in[4];
    float* out = (float*)d_out;

    // Two IDENTICAL dispatches (deterministic: same values written twice).
    // dur = F + T_coldL3 + T_warmL3; round-5 anchor: F + T_coldL3 = 51.2us.
    qgemm<<<688, 256, 0, stream>>>(x, wqp, sc, zp, bp, out);
    qgemm<<<688, 256, 0, stream>>>(x, wqp, sc, zp, bp, out);
}

// Round 9
// 59.108 us; speedup vs baseline: 1.6463x; 1.6463x over previous
//
#include <hip/hip_runtime.h>
#include <hip/hip_fp16.h>

// QuantLinear: out[16][11008] = x[16][4096] . dequant(weight_q[11008][4096])^T + bias
// Harness promotes fp16 tensors to fp32 -> x/scale/zero/bias are float*.
// Ladder: 55.2 (split-K atomics) -> 51.2 (1-kernel) -> invariant to occupancy
// (x2,x4), coalescing (LDS staging), atomics. Round-8 double-dispatch: 2nd
// (L3-warm) pass = 46us -> reads run at ~4 TB/s FROM L3; launch overhead F~5us.
// Theory: per-CU MSHR/latency limit, with HALF of VMEM instrs wasted on x
// re-loads (256KB x L1-missing every iteration) + weights thrashing L2.
// This round: (1) x hoisted to VGPRs once (8 waves x 512-k window, 16 MFMA
// A-frags = 64 VGPRs f16); steady-state VMEM = weight loads ONLY;
// (2) non-temporal weight loads (no L2 allocate for the dead 180MB stream).

typedef _Float16 v8hf __attribute__((ext_vector_type(8)));
typedef float    v4f  __attribute__((ext_vector_type(4)));
typedef int      v4i  __attribute__((ext_vector_type(4)));

#define O_DIM 11008
#define I_DIM 4096
#define NGROUP 32   // I_DIM / 128

__global__ __launch_bounds__(512) void qgemm(const float* __restrict__ x,
                                             const int* __restrict__ wq,
                                             const float* __restrict__ scale,
                                             const float* __restrict__ zero,
                                             const float* __restrict__ bias,
                                             float* __restrict__ out) {
    __shared__ float red[8][256];

    const int ot  = blockIdx.x;    // o-tile 0..687
    const int tid = threadIdx.x;
    const int w   = tid >> 6;      // wave 0..7 -> 512-wide K window
    const int l   = tid & 63;
    const int col = l & 15;        // A-row = x-row / B-col = o (within tile)
    const int kb  = l >> 4;        // k sub-block 0..3
    const int o   = ot * 16 + col;
    const int k0  = w * 512;       // wave's K base

    // ---- x preload: 16 MFMA A-fragments (f16) for this wave's K window ----
    v8hf a_reg[16];
#pragma unroll
    for (int i = 0; i < 16; ++i) {
        const float* xp = x + (size_t)col * I_DIM + k0 + i * 32 + kb * 8;
        const float4 x0 = *(const float4*)(xp);
        const float4 x1 = *(const float4*)(xp + 4);
        a_reg[i][0] = (_Float16)x0.x; a_reg[i][1] = (_Float16)x0.y;
        a_reg[i][2] = (_Float16)x0.z; a_reg[i][3] = (_Float16)x0.w;
        a_reg[i][4] = (_Float16)x1.x; a_reg[i][5] = (_Float16)x1.y;
        a_reg[i][6] = (_Float16)x1.z; a_reg[i][7] = (_Float16)x1.w;
    }
    // ---- scale/zero preload for this wave's 4 groups ----
    float s_[4], nzs_[4];
#pragma unroll
    for (int gi = 0; gi < 4; ++gi) {
        const int g = w * 4 + gi;
        const float s = scale[o * NGROUP + g];
        const float z = zero [o * NGROUP + g];
        s_[gi] = s; nzs_[gi] = -z * s;
    }

    const int* __restrict__ wrow = wq + (size_t)o * I_DIM;
    v4f acc = {0.f, 0.f, 0.f, 0.f};

    // Steady state: ONLY weight loads on the VMEM path, non-temporal.
#pragma unroll
    for (int gi = 0; gi < 4; ++gi) {
        const float s = s_[gi], nzs = nzs_[gi];
#pragma unroll
        for (int ks = 0; ks < 4; ++ks) {
            const int i0 = k0 + gi * 128 + ks * 32 + kb * 8;   // lane's 8 k's
            const v4i q0 = __builtin_nontemporal_load((const v4i*)(wrow + i0));
            const v4i q1 = __builtin_nontemporal_load((const v4i*)(wrow + i0) + 1);
            v8hf bf;   // same (lane,j)->k mapping as A => permutation cancels
            bf[0] = (_Float16)((float)(q0[0] & 255) * s + nzs);
            bf[1] = (_Float16)((float)(q0[1] & 255) * s + nzs);
            bf[2] = (_Float16)((float)(q0[2] & 255) * s + nzs);
            bf[3] = (_Float16)((float)(q0[3] & 255) * s + nzs);
            bf[4] = (_Float16)((float)(q1[0] & 255) * s + nzs);
            bf[5] = (_Float16)((float)(q1[1] & 255) * s + nzs);
            bf[6] = (_Float16)((float)(q1[2] & 255) * s + nzs);
            bf[7] = (_Float16)((float)(q1[3] & 255) * s + nzs);
            acc = __builtin_amdgcn_mfma_f32_16x16x32_f16(a_reg[gi * 4 + ks], bf,
                                                         acc, 0, 0, 0);
        }
    }

    // Cross-wave K-reduce (8 partials). acc[r] = C[row=(l>>4)*4+r][col].
    *(v4f*)&red[w][l * 4] = acc;
    __syncthreads();

    if (tid < 256) {
        float sum = red[0][tid] + red[1][tid] + red[2][tid] + red[3][tid]
                  + red[4][tid] + red[5][tid] + red[6][tid] + red[7][tid];
        const int l2  = tid >> 2;               // original lane
        const int r   = tid & 3;                // acc register index
        const int row = (l2 >> 4) * 4 + r;      // x-row 0..15
        const int oc  = ot * 16 + (l2 & 15);    // output column
        out[(size_t)row * O_DIM + oc] = sum + bias[oc];
    }
}

extern "C" void kernel_launch(void* const* d_in, const int* in_sizes, int n_in,
                              void* d_out, int out_size, void* d_ws, size_t ws_size,
                              hipStream_t stream) {
    const float* x   = (const float*)d_in[0];
    const int*   wqp = (const int*)  d_in[1];
    const float* sc  = (const float*)d_in[2];
    const float* zp  = (const float*)d_in[3];
    const float* bp  = (const float*)d_in[4];
    float* out = (float*)d_out;

    qgemm<<<688, 512, 0, stream>>>(x, wqp, sc, zp, bp, out);
}

// Round 10
// 49.936 us; speedup vs baseline: 1.9486x; 1.1837x over previous
//
#include <hip/hip_runtime.h>
#include <hip/hip_fp16.h>

// QuantLinear: out[16][11008] = x[16][4096] . dequant(weight_q[11008][4096])^T + bias
// Harness promotes fp16 tensors to fp32 -> x/scale/zero/bias are float*.
// Model (rounds 2-9): weight reads pinned at ~4 TB/s regardless of occupancy,
// coalescing, atomics, source (L3-warm == HBM-cold, round 8) -> per-CU
// outstanding-line (MSHR) limit on the read path to the IOD; floor ~45us +
// ~5us fixed replay overhead. Round-9 (x-hoist + nt) = 59.1: TWO changes.
// This round isolates: x-hoist WITHOUT nt. If x's L2-hit lines were occupying
// MSHR slots, freeing them helps (46-50); if neutral, round-5 (51.2) is the
// ceiling and we declare roofline.

typedef _Float16 v8hf __attribute__((ext_vector_type(8)));
typedef float    v4f  __attribute__((ext_vector_type(4)));

#define O_DIM 11008
#define I_DIM 4096
#define NGROUP 32   // I_DIM / 128

__global__ __launch_bounds__(512) void qgemm(const float* __restrict__ x,
                                             const int* __restrict__ wq,
                                             const float* __restrict__ scale,
                                             const float* __restrict__ zero,
                                             const float* __restrict__ bias,
                                             float* __restrict__ out) {
    __shared__ float red[8][256];

    const int ot  = blockIdx.x;    // o-tile 0..687
    const int tid = threadIdx.x;
    const int w   = tid >> 6;      // wave 0..7 -> 512-wide K window
    const int l   = tid & 63;
    const int col = l & 15;        // A-row = x-row / B-col = o (within tile)
    const int kb  = l >> 4;        // k sub-block 0..3
    const int o   = ot * 16 + col;
    const int k0  = w * 512;       // wave's K base

    // ---- x preload: 16 MFMA A-fragments (f16) for this wave's K window ----
    v8hf a_reg[16];
#pragma unroll
    for (int i = 0; i < 16; ++i) {
        const float* xp = x + (size_t)col * I_DIM + k0 + i * 32 + kb * 8;
        const float4 x0 = *(const float4*)(xp);
        const float4 x1 = *(const float4*)(xp + 4);
        a_reg[i][0] = (_Float16)x0.x; a_reg[i][1] = (_Float16)x0.y;
        a_reg[i][2] = (_Float16)x0.z; a_reg[i][3] = (_Float16)x0.w;
        a_reg[i][4] = (_Float16)x1.x; a_reg[i][5] = (_Float16)x1.y;
        a_reg[i][6] = (_Float16)x1.z; a_reg[i][7] = (_Float16)x1.w;
    }
    // ---- scale/zero preload for this wave's 4 groups ----
    float s_[4], nzs_[4];
#pragma unroll
    for (int gi = 0; gi < 4; ++gi) {
        const int g = w * 4 + gi;
        const float s = scale[o * NGROUP + g];
        const float z = zero [o * NGROUP + g];
        s_[gi] = s; nzs_[gi] = -z * s;
    }

    const int* __restrict__ wrow = wq + (size_t)o * I_DIM;
    v4f acc = {0.f, 0.f, 0.f, 0.f};

    // Steady state: ONLY weight loads on the VMEM path (plain, cacheable).
#pragma unroll
    for (int gi = 0; gi < 4; ++gi) {
        const float s = s_[gi], nzs = nzs_[gi];
#pragma unroll
        for (int ks = 0; ks < 4; ++ks) {
            const int i0 = k0 + gi * 128 + ks * 32 + kb * 8;   // lane's 8 k's
            const int4 q0 = *(const int4*)(wrow + i0);
            const int4 q1 = *(const int4*)(wrow + i0 + 4);
            v8hf bf;   // same (lane,j)->k mapping as A => permutation cancels
            bf[0] = (_Float16)((float)(q0.x & 255) * s + nzs);
            bf[1] = (_Float16)((float)(q0.y & 255) * s + nzs);
            bf[2] = (_Float16)((float)(q0.z & 255) * s + nzs);
            bf[3] = (_Float16)((float)(q0.w & 255) * s + nzs);
            bf[4] = (_Float16)((float)(q1.x & 255) * s + nzs);
            bf[5] = (_Float16)((float)(q1.y & 255) * s + nzs);
            bf[6] = (_Float16)((float)(q1.z & 255) * s + nzs);
            bf[7] = (_Float16)((float)(q1.w & 255) * s + nzs);
            acc = __builtin_amdgcn_mfma_f32_16x16x32_f16(a_reg[gi * 4 + ks], bf,
                                                         acc, 0, 0, 0);
        }
    }

    // Cross-wave K-reduce (8 partials). acc[r] = C[row=(l>>4)*4+r][col].
    *(v4f*)&red[w][l * 4] = acc;
    __syncthreads();

    if (tid < 256) {
        float sum = red[0][tid] + red[1][tid] + red[2][tid] + red[3][tid]
                  + red[4][tid] + red[5][tid] + red[6][tid] + red[7][tid];
        const int l2  = tid >> 2;               // original lane
        const int r   = tid & 3;                // acc register index
        const int row = (l2 >> 4) * 4 + r;      // x-row 0..15
        const int oc  = ot * 16 + (l2 & 15);    // output column
        out[(size_t)row * O_DIM + oc] = sum + bias[oc];
    }
}

extern "C" void kernel_launch(void* const* d_in, const int* in_sizes, int n_in,
                              void* d_out, int out_size, void* d_ws, size_t ws_size,
                              hipStream_t stream) {
    const float* x   = (const float*)d_in[0];
    const int*   wqp = (const int*)  d_in[1];
    const float* sc  = (const float*)d_in[2];
    const float* zp  = (const float*)d_in[3];
    const float* bp  = (const float*)d_in[4];
    float* out = (float*)d_out;

    qgemm<<<688, 512, 0, stream>>>(x, wqp, sc, zp, bp, out);
}